// Round 11
// baseline (232.108 us; speedup 1.0000x reference)
//
#include <hip/hip_runtime.h>
#include <hip/hip_bf16.h>

// MultiHeadSelfAttention: B=2, S=2048, D=1024, H=16, Dh=64, RoPE theta=1e4, causal.
// Round 11: attn per-tile restructure: Q-frags pinned in VGPRs (Qs deleted);
// K/V staged via global_load_lds (XOR chunk swizzle) double-buffered, ONE barrier
// per tile (DMA for kt+1 issues after barrier publishing kt -> latency hidden by
// compute phase). Split-K/combine/qkv/out_proj/conv unchanged from round 10.
// ws (u16): Q|K|Vt|AO(=Xbf)|Wbf (40MB) + Opart (21MB) + Lpart (0.7MB).

#define D_MODEL 1024
#define NHEADS  16
#define HDIM    64
#define SEQ     2048
#define BATCH   2

typedef unsigned short u16;
typedef __bf16 bf16x8_t __attribute__((ext_vector_type(8)));
typedef float  f32x4_t  __attribute__((ext_vector_type(4)));

__device__ __forceinline__ u16 f2bf(float f) {
    union { __hip_bfloat16 h; u16 u; } cv;
    cv.h = __float2bfloat16(f);
    return cv.u;
}

__device__ __forceinline__ unsigned pk2(float x, float y) {
    union { __hip_bfloat162 h; unsigned u; } cv;
    cv.h = __float22bfloat162_rn(make_float2(x, y));   // v_cvt_pk_bf16_f32
    return cv.u;
}

__device__ __forceinline__ uint4 pack8(float4 a, float4 b) {
    uint4 u;
    u.x = pk2(a.x, a.y);
    u.y = pk2(a.z, a.w);
    u.z = pk2(b.x, b.y);
    u.w = pk2(b.z, b.w);
    return u;
}

__device__ __forceinline__ bf16x8_t frag_ld(const u16* p) {
    union { uint4 u; bf16x8_t v; } t;
    t.u = *(const uint4*)p;
    return t.v;
}

// unpack 4 bf16-pairs (uint4) -> add into 8 fp32 accumulators
__device__ __forceinline__ void acc8(uint4 u, float* a) {
    a[0] += __uint_as_float(u.x << 16); a[1] += __uint_as_float(u.x & 0xffff0000u);
    a[2] += __uint_as_float(u.y << 16); a[3] += __uint_as_float(u.y & 0xffff0000u);
    a[4] += __uint_as_float(u.z << 16); a[5] += __uint_as_float(u.z & 0xffff0000u);
    a[6] += __uint_as_float(u.w << 16); a[7] += __uint_as_float(u.w & 0xffff0000u);
}

// async global->LDS DMA, 16B/lane; LDS dest = wave-uniform base + lane*16
__device__ __forceinline__ void dma16(const u16* g, u16* l) {
    __builtin_amdgcn_global_load_lds(
        (const __attribute__((address_space(1))) void*)g,
        (__attribute__((address_space(3))) void*)l, 16, 0, 0);
}

// ---------------------------------------------------------------------------
// fp32 -> bf16 conversion: X (4M elems) -> Xbf, Wq|Wk|Wv|Wo (1M each) -> Wbf.
// ---------------------------------------------------------------------------
__global__ __launch_bounds__(256) void conv_bf16_kernel(
    const float* __restrict__ X, const float* __restrict__ Wq,
    const float* __restrict__ Wk, const float* __restrict__ Wv,
    const float* __restrict__ Wo, u16* __restrict__ Xbf, u16* __restrict__ Wbf)
{
    const size_t gid = (size_t)blockIdx.x * 256 + threadIdx.x;
    const float* src;
    u16* dst;
    size_t off;
    if (gid < (1u << 19)) {                     // X: 4M elems / 8
        src = X; dst = Xbf; off = gid;
    } else {
        size_t g = gid - (1u << 19);
        const int wsel = (int)(g >> 17);        // 1M elems / 8 per W
        g &= (1u << 17) - 1;
        src = (wsel == 0) ? Wq : (wsel == 1) ? Wk : (wsel == 2) ? Wv : Wo;
        dst = Wbf + ((size_t)wsel << 20);
        off = g;
    }
    const float4 a = *(const float4*)(src + off * 8);
    const float4 b = *(const float4*)(src + off * 8 + 4);
    *(uint4*)(dst + off * 8) = pack8(a, b);
}

// ---------------------------------------------------------------------------
// QKV projection + RoPE, m97-style DMA staging (round 9, unchanged).
// ---------------------------------------------------------------------------
__global__ __launch_bounds__(256) void qkv_rope_kernel(
    const u16* __restrict__ Xbf, const u16* __restrict__ Wbf,
    const int* __restrict__ pos,
    u16* __restrict__ Qo, u16* __restrict__ Ko, u16* __restrict__ Vt)
{
    __shared__ __align__(16) u16 smem[16896];   // staging 2x8192 ∪ Ts 128x132
    u16* As = smem;                             // [128][64] raw
    u16* Bs = smem + 8192;

    const int tid = threadIdx.x;
    const int m0 = blockIdx.y * 128;
    const int nv = blockIdx.x * 128;
    const int which = nv >> 10;                 // 0=q,1=k,2=v
    const int nbase = nv & 1023;
    const u16* __restrict__ Wsrc = Wbf + ((size_t)which << 20);

    const int w = tid >> 6, L = tid & 63, quad = L >> 4, colL = L & 15;
    const int mw = (w & 1) * 64, nw = (w >> 1) * 64;

    const int lrow = L >> 3;
    const int lchk = (L & 7) ^ lrow;            // XOR chunk swizzle
    const u16* ag = Xbf + (size_t)(m0 + 32 * w + lrow) * D_MODEL + lchk * 8;
    const u16* bg = Wsrc + (size_t)(nbase + 32 * w + lrow) * D_MODEL + lchk * 8;
    u16* al = As + (32 * w) * 64;
    u16* bl = Bs + (32 * w) * 64;

    f32x4_t acc[4][4];
    #pragma unroll
    for (int i = 0; i < 4; ++i)
        #pragma unroll
        for (int j = 0; j < 4; ++j) acc[i][j] = (f32x4_t){0.f, 0.f, 0.f, 0.f};

    for (int k0 = 0; k0 < D_MODEL; k0 += 64) {
        __syncthreads();
        #pragma unroll
        for (int j = 0; j < 4; ++j) {
            dma16(ag + (size_t)j * 8 * D_MODEL + k0, al + j * 512);
            dma16(bg + (size_t)j * 8 * D_MODEL + k0, bl + j * 512);
        }
        __syncthreads();
        #pragma unroll
        for (int kb = 0; kb < 2; ++kb) {
            const int ch = ((kb * 4 + quad) ^ (colL & 7)) * 8;
            bf16x8_t af[4], bf[4];
            #pragma unroll
            for (int t = 0; t < 4; ++t) {
                af[t] = frag_ld(As + (mw + t * 16 + colL) * 64 + ch);
                bf[t] = frag_ld(Bs + (nw + t * 16 + colL) * 64 + ch);
            }
            #pragma unroll
            for (int mt = 0; mt < 4; ++mt)
                #pragma unroll
                for (int nt = 0; nt < 4; ++nt)
                    acc[mt][nt] = __builtin_amdgcn_mfma_f32_16x16x32_bf16(
                        af[mt], bf[nt], acc[mt][nt], 0, 0, 0);
        }
    }

    __syncthreads();
    u16 (*Ts)[132] = (u16(*)[132])smem;

    const float C0 = 0.14391156831212787f;      // ln(10000)/64
    if (which < 2) {
        const float oscale = (which == 0) ? 0.125f : 1.0f;
        float invf[4], sgn[4];
        #pragma unroll
        for (int nt = 0; nt < 4; ++nt) {
            const int n = nbase + nw + nt * 16 + colL;
            const int dd = n & 63;
            invf[nt] = __expf(-(float)(dd & 62) * C0);
            sgn[nt] = (dd & 1) ? 1.0f : -1.0f;
        }
        #pragma unroll
        for (int mt = 0; mt < 4; ++mt) {
            #pragma unroll
            for (int r = 0; r < 4; ++r) {
                const int ml = mw + mt * 16 + quad * 4 + r;
                const int ss = (m0 + ml) & 2047;
                const float p = (float)pos[ss];
                #pragma unroll
                for (int nt = 0; nt < 4; ++nt) {
                    const float v = acc[mt][nt][r];
                    const float partner = __shfl_xor(v, 1);
                    float sn, cs;
                    __sincosf(p * invf[nt], &sn, &cs);
                    Ts[ml][nw + nt * 16 + colL] =
                        f2bf((v * cs + sgn[nt] * sn * partner) * oscale);
                }
            }
        }
    } else {
        #pragma unroll
        for (int mt = 0; mt < 4; ++mt)
            #pragma unroll
            for (int nt = 0; nt < 4; ++nt)
                #pragma unroll
                for (int r = 0; r < 4; ++r)
                    Ts[nw + nt * 16 + colL][mw + mt * 16 + quad * 4 + r] = f2bf(acc[mt][nt][r]);
    }
    __syncthreads();

    const int rr0 = tid >> 4;
    const int cc8 = (tid & 15) * 8;
    if (which < 2) {
        u16* __restrict__ dst = (which == 0) ? Qo : Ko;
        #pragma unroll
        for (int it = 0; it < 8; ++it) {
            const int ml = rr0 + it * 16;
            const int m = m0 + ml, bb = m >> 11, ss = m & 2047;
            const int n = nbase + cc8, h = n >> 6, d = n & 63;
            *(uint4*)&dst[((size_t)(bb * NHEADS + h) * SEQ + ss) * HDIM + d] =
                *(const uint4*)&Ts[ml][cc8];
        }
    } else {
        const int bb = m0 >> 11, ss0 = (m0 & 2047) + cc8;
        #pragma unroll
        for (int it = 0; it < 8; ++it) {
            const int nl = rr0 + it * 16;
            const int n = nbase + nl, h = n >> 6, d = n & 63;
            *(uint4*)&Vt[((size_t)(bb * NHEADS + h) * HDIM + d) * SEQ + ss0] =
                *(const uint4*)&Ts[nl][cc8];
        }
    }
}

// ---------------------------------------------------------------------------
// Split-K flash attention (causal, max-free). Q-frags in VGPRs; K/V via dma16
// XOR-swizzled double-buffered LDS; ONE __syncthreads per k-tile.
// slot layout per (b,h): qt=8g+r has g+1 chunks; base(qt)=4g(g+1)+r(g+1); 80 total.
// ---------------------------------------------------------------------------
__global__ __launch_bounds__(256) void attn_kernel(
    const u16* __restrict__ Q, const u16* __restrict__ K,
    const u16* __restrict__ Vt, u16* __restrict__ Opart, float* __restrict__ Lpart)
{
    __shared__ __align__(16) u16 Kb[2][64 * 64];   // [key][d] raw, XOR-swizzled chunks
    __shared__ __align__(16) u16 Vb[2][64 * 64];   // [d][key] raw, XOR-swizzled chunks
    __shared__ __align__(16) u16 Ps[4][16][72];    // per-wave [q_local][key]

    const int tid = threadIdx.x;
    const int slot = 79 - (int)blockIdx.x;      // LPT: deepest chunks first
    const int g = (slot >= 48) ? 3 : (slot >= 24) ? 2 : (slot >= 8) ? 1 : 0;
    const int t0 = slot - 4 * g * (g + 1);
    const int rr = t0 / (g + 1);
    const int s  = t0 - rr * (g + 1);
    const int qt = 8 * g + rr;

    const int hh = blockIdx.y, bb = blockIdx.z;
    const size_t bh = ((size_t)bb * NHEADS + hh) * (SEQ * HDIM);
    const int q0 = qt * 64;
    const int kt0 = s * 8;
    const int ktend = min(kt0 + 8, qt + 1);
    const size_t gslot = ((size_t)(bb * NHEADS + hh) * 80 + slot);

    const int w = tid >> 6, L = tid & 63, quad = L >> 4, colL = L & 15;

    // Q A-frags pinned in registers (pre-scaled by 1/8 in qkv)
    const u16* qp = Q + bh + (size_t)(q0 + w * 16 + colL) * HDIM + quad * 8;
    const bf16x8_t aq0 = frag_ld(qp);
    const bf16x8_t aq1 = frag_ld(qp + 32);

    // DMA lane mapping: per instr j, wave w stages rows w*16+j*8+(L>>3),
    // physical chunk L&7 holds source chunk (L&7)^(L>>3)  (XOR swizzle).
    const int drow = L >> 3;
    const int dchk = (L & 7) ^ drow;
    const u16* kg = K + bh + (size_t)(w * 16 + drow) * HDIM + dchk * 8;
    const u16* vg = Vt + bh + (size_t)(w * 16 + drow) * SEQ + dchk * 8;
    const int ldso = (w * 16) * 64;             // wave-uniform LDS row base

    float lsum[4] = {0.f, 0.f, 0.f, 0.f};
    f32x4_t O[4];
    #pragma unroll
    for (int dt = 0; dt < 4; ++dt) O[dt] = (f32x4_t){0.f, 0.f, 0.f, 0.f};

    // stage first tile into buffer 0
    {
        const int k0 = kt0 * 64;
        #pragma unroll
        for (int j = 0; j < 2; ++j) {
            dma16(kg + (size_t)(k0 + j * 8) * HDIM, Kb[0] + ldso + j * 512);
            dma16(vg + (size_t)(j * 8) * SEQ + k0,  Vb[0] + ldso + j * 512);
        }
    }

    int p = 0;
    const int ch0 = (quad ^ (colL & 7)) * 8;          // kb=0 swizzled chunk offset
    const int ch1 = ((4 + quad) ^ (colL & 7)) * 8;    // kb=1

    for (int kt = kt0; kt < ktend; ++kt) {
        __syncthreads();          // drains DMA for buf p; all waves done reading buf p^1

        if (kt + 1 < ktend) {     // stage next tile into the other buffer
            const int k1 = (kt + 1) * 64;
            #pragma unroll
            for (int j = 0; j < 2; ++j) {
                dma16(kg + (size_t)(k1 + j * 8) * HDIM, Kb[p ^ 1] + ldso + j * 512);
                dma16(vg + (size_t)(j * 8) * SEQ + k1,  Vb[p ^ 1] + ldso + j * 512);
            }
        }

        const u16* Kc = Kb[p];
        const u16* Vc = Vb[p];
        const bool diag = (kt == qt);
        const int ntmax = diag ? w : 3;         // wave-uniform causal pruning

        f32x4_t S[4];
        #pragma unroll
        for (int nt = 0; nt < 4; ++nt) S[nt] = (f32x4_t){0.f, 0.f, 0.f, 0.f};
        for (int nt = 0; nt <= ntmax; ++nt) {
            const u16* kr = Kc + (nt * 16 + colL) * 64;
            S[nt] = __builtin_amdgcn_mfma_f32_16x16x32_bf16(aq0, frag_ld(kr + ch0), S[nt], 0, 0, 0);
            S[nt] = __builtin_amdgcn_mfma_f32_16x16x32_bf16(aq1, frag_ld(kr + ch1), S[nt], 0, 0, 0);
        }

        // max-free: p = exp(s); per-lane partial l; masked/pruned -> 0
        #pragma unroll
        for (int r = 0; r < 4; ++r) {
            const int qa = q0 + w * 16 + quad * 4 + r;
            #pragma unroll
            for (int nt = 0; nt < 4; ++nt) {
                float pv = 0.0f;
                if (nt <= ntmax) {
                    const int key = kt * 64 + nt * 16 + colL;
                    pv = (!diag || key <= qa) ? __expf(S[nt][r]) : 0.0f;
                }
                lsum[r] += pv;
                Ps[w][quad * 4 + r][nt * 16 + colL] = f2bf(pv);
            }
        }

        asm volatile("s_waitcnt lgkmcnt(0)" ::: "memory");  // wave-local Ps ready

        const int kbmax = diag ? (w >> 1) : 1;
        for (int kb = 0; kb <= kbmax; ++kb) {
            const bf16x8_t ap = frag_ld(&Ps[w][colL][kb * 32 + quad * 8]);
            const int chv = ((kb * 4 + quad) ^ (colL & 7)) * 8;
            #pragma unroll
            for (int dt = 0; dt < 4; ++dt) {
                const bf16x8_t bv = frag_ld(Vc + (dt * 16 + colL) * 64 + chv);
                O[dt] = __builtin_amdgcn_mfma_f32_16x16x32_bf16(ap, bv, O[dt], 0, 0, 0);
            }
        }
        p ^= 1;
    }

    // l partial: reduce over the 16 lanes of each quad-row; lane colL==0 writes
    #pragma unroll
    for (int r = 0; r < 4; ++r) {
        float sm = lsum[r];
        #pragma unroll
        for (int off = 1; off < 16; off <<= 1) sm += __shfl_xor(sm, off);
        if (colL == 0)
            Lpart[gslot * 64 + 16 * w + quad * 4 + r] = sm;
    }

    // O partial (unnormalized bf16): C-layout -> per-wave LDS -> coalesced stores
    #pragma unroll
    for (int dt = 0; dt < 4; ++dt)
        #pragma unroll
        for (int r = 0; r < 4; ++r)
            Ps[w][quad * 4 + r][dt * 16 + colL] = f2bf(O[dt][r]);
    asm volatile("s_waitcnt lgkmcnt(0)" ::: "memory");
    #pragma unroll
    for (int pp = 0; pp < 2; ++pp) {
        const int rowl = (L >> 3) + 8 * pp;     // 0..15
        const int c8 = (L & 7) * 8;             // 0..56
        *(uint4*)&Opart[gslot * 4096 + (size_t)(16 * w + rowl) * 64 + c8] =
            *(const uint4*)&Ps[w][rowl][c8];
    }
}

// ---------------------------------------------------------------------------
// Combine: AO[b,s,h*d] = (sum_s Opart) / (sum_s Lpart). Block = (qt, hh, bb).
// ---------------------------------------------------------------------------
__global__ __launch_bounds__(256) void combine_kernel(
    const u16* __restrict__ Opart, const float* __restrict__ Lpart,
    u16* __restrict__ AO)
{
    const int qt = blockIdx.x, hh = blockIdx.y, bb = blockIdx.z;
    const int g = qt >> 3;
    const int nsplit = g + 1;
    const int base = 4 * g * (g + 1) + (qt & 7) * (g + 1);
    const int t = threadIdx.x;
    const int q = t >> 2, dg = (t & 3) * 16;
    const size_t slot0 = (size_t)(bb * NHEADS + hh) * 80 + base;

    float acc[16];
    #pragma unroll
    for (int i = 0; i < 16; ++i) acc[i] = 0.f;
    float l = 0.f;
    for (int s = 0; s < nsplit; ++s) {
        const size_t gs = slot0 + s;
        l += Lpart[gs * 64 + q];
        const u16* op = Opart + gs * 4096 + (size_t)q * 64 + dg;
        acc8(*(const uint4*)op, acc);
        acc8(*(const uint4*)(op + 8), acc + 8);
    }
    const float inv = 1.0f / l;
    uint4 o0, o1;
    o0.x = pk2(acc[0] * inv, acc[1] * inv);  o0.y = pk2(acc[2] * inv, acc[3] * inv);
    o0.z = pk2(acc[4] * inv, acc[5] * inv);  o0.w = pk2(acc[6] * inv, acc[7] * inv);
    o1.x = pk2(acc[8] * inv, acc[9] * inv);  o1.y = pk2(acc[10] * inv, acc[11] * inv);
    o1.z = pk2(acc[12] * inv, acc[13] * inv); o1.w = pk2(acc[14] * inv, acc[15] * inv);
    u16* dst = AO + ((size_t)bb * SEQ + qt * 64 + q) * D_MODEL + hh * HDIM + dg;
    *(uint4*)dst = o0;
    *(uint4*)(dst + 8) = o1;
}

// ---------------------------------------------------------------------------
// Output projection: Out(fp32) = AO(bf16) * Wo_bf^T, m97-style DMA staging.
// ---------------------------------------------------------------------------
__global__ __launch_bounds__(256) void out_proj_kernel(
    const u16* __restrict__ A, const u16* __restrict__ Wob, float* __restrict__ Out)
{
    __shared__ __align__(16) u16 smem[16384];
    u16* As = smem;
    u16* Bs = smem + 8192;

    const int tid = threadIdx.x;
    const int m0 = blockIdx.y * 128;
    const int n0 = blockIdx.x * 128;

    const int w = tid >> 6, L = tid & 63, quad = L >> 4, colL = L & 15;
    const int mw = (w & 1) * 64, nw = (w >> 1) * 64;

    const int lrow = L >> 3;
    const int lchk = (L & 7) ^ lrow;
    const u16* ag = A + (size_t)(m0 + 32 * w + lrow) * D_MODEL + lchk * 8;
    const u16* bg = Wob + (size_t)(n0 + 32 * w + lrow) * D_MODEL + lchk * 8;
    u16* al = As + (32 * w) * 64;
    u16* bl = Bs + (32 * w) * 64;

    f32x4_t acc[4][4];
    #pragma unroll
    for (int i = 0; i < 4; ++i)
        #pragma unroll
        for (int j = 0; j < 4; ++j) acc[i][j] = (f32x4_t){0.f, 0.f, 0.f, 0.f};

    for (int k0 = 0; k0 < D_MODEL; k0 += 64) {
        __syncthreads();
        #pragma unroll
        for (int j = 0; j < 4; ++j) {
            dma16(ag + (size_t)j * 8 * D_MODEL + k0, al + j * 512);
            dma16(bg + (size_t)j * 8 * D_MODEL + k0, bl + j * 512);
        }
        __syncthreads();
        #pragma unroll
        for (int kb = 0; kb < 2; ++kb) {
            const int ch = ((kb * 4 + quad) ^ (colL & 7)) * 8;
            bf16x8_t af[4], bf[4];
            #pragma unroll
            for (int t = 0; t < 4; ++t) {
                af[t] = frag_ld(As + (mw + t * 16 + colL) * 64 + ch);
                bf[t] = frag_ld(Bs + (nw + t * 16 + colL) * 64 + ch);
            }
            #pragma unroll
            for (int mt = 0; mt < 4; ++mt)
                #pragma unroll
                for (int nt = 0; nt < 4; ++nt)
                    acc[mt][nt] = __builtin_amdgcn_mfma_f32_16x16x32_bf16(
                        af[mt], bf[nt], acc[mt][nt], 0, 0, 0);
        }
    }

    #pragma unroll
    for (int mt = 0; mt < 4; ++mt)
        #pragma unroll
        for (int nt = 0; nt < 4; ++nt)
            #pragma unroll
            for (int r = 0; r < 4; ++r) {
                const int m = m0 + mw + mt * 16 + quad * 4 + r;
                const int n = n0 + nw + nt * 16 + colL;
                Out[(size_t)m * D_MODEL + n] = acc[mt][nt][r];
            }
}

// ---------------------------------------------------------------------------
extern "C" void kernel_launch(void* const* d_in, const int* in_sizes, int n_in,
                              void* d_out, int out_size, void* d_ws, size_t ws_size,
                              hipStream_t stream) {
    const float* x  = (const float*)d_in[0];
    const float* wq = (const float*)d_in[1];
    const float* wk = (const float*)d_in[2];
    const float* wv = (const float*)d_in[3];
    const float* wo = (const float*)d_in[4];
    const int* pos  = (const int*)d_in[5];
    float* out = (float*)d_out;

    const size_t NELEM = (size_t)BATCH * NHEADS * SEQ * HDIM;  // 4,194,304
    u16* Qw  = (u16*)d_ws;
    u16* Kw  = Qw + NELEM;
    u16* Vtw = Kw + NELEM;
    u16* AOw = Vtw + NELEM;        // doubles as Xbf (attn writes after qkv reads)
    u16* Xbf = AOw;
    u16* Wbf = AOw + NELEM;        // 4M elems (wq|wk|wv|wo)
    u16* Opart = Wbf + NELEM;      // 2560 slots x 4096 u16 = 21MB
    float* Lpart = (float*)(Opart + (size_t)2560 * 4096);  // 2560 x 64 fp32

    conv_bf16_kernel<<<4096, 256, 0, stream>>>(x, wq, wk, wv, wo, Xbf, Wbf);
    qkv_rope_kernel<<<dim3(24, 32), 256, 0, stream>>>(Xbf, Wbf, pos, Qw, Kw, Vtw);
    attn_kernel<<<dim3(80, NHEADS, BATCH), 256, 0, stream>>>(Qw, Kw, Vtw, Opart, Lpart);
    combine_kernel<<<dim3(32, NHEADS, BATCH), 256, 0, stream>>>(Opart, Lpart, AOw);
    out_proj_kernel<<<dim3(8, 32), 256, 0, stream>>>(AOw, Wbf + 3 * (1u << 20), out);
}